// Round 5
// baseline (891.357 us; speedup 1.0000x reference)
//
#include <hip/hip_runtime.h>
#include <cstdint>
#include <cstddef>

#define N_TOK  8192
#define HDIM   2048
#define NEXP   8
#define KCAP   1024
#define DFF    5461
#define DFF_PB 5504   // padded rows for WgT/WuT (N of gemm1)
#define ACT_P  5504   // act row pitch / gemm2 K (multiple of 64)
#define NT1    (HDIM / 64)    // 32
#define NT2    (ACT_P / 64)   // 86

typedef unsigned short u16;
typedef short bf16x8 __attribute__((ext_vector_type(8)));
typedef float f32x4  __attribute__((ext_vector_type(4)));

__device__ __forceinline__ u16 f2bf(float f) {
  uint32_t u = __float_as_uint(f);
  uint32_t r = (u + 0x7FFFu + ((u >> 16) & 1u)) >> 16;
  return (u16)r;
}

__device__ __forceinline__ uint32_t rotl32(uint32_t v, int d) {
  return (v << d) | (v >> (32 - d));
}

// JAX threefry2x32, key = (0, 42), partitionable scheme: counter=(0,i), bits = x0^x1.
__device__ uint32_t threefry_bits(uint32_t idx) {
  const uint32_t ks0 = 0u, ks1 = 42u, ks2 = 0u ^ 42u ^ 0x1BD11BDAu;
  uint32_t x0 = 0u + ks0;
  uint32_t x1 = idx + ks1;
#define TFR(d) { x0 += x1; x1 = rotl32(x1, d); x1 ^= x0; }
  TFR(13) TFR(15) TFR(26) TFR(6)
  x0 += ks1; x1 += ks2 + 1u;
  TFR(17) TFR(29) TFR(16) TFR(24)
  x0 += ks2; x1 += ks0 + 2u;
  TFR(13) TFR(15) TFR(26) TFR(6)
  x0 += ks0; x1 += ks1 + 3u;
  TFR(17) TFR(29) TFR(16) TFR(24)
  x0 += ks1; x1 += ks2 + 4u;
  TFR(13) TFR(15) TFR(26) TFR(6)
  x0 += ks2; x1 += ks0 + 5u;
#undef TFR
  return x0 ^ x1;
}

// ---------------- router: clean_h + gumbel -> softmax, stored transposed [E][n_tok]
__global__ __launch_bounds__(256) void router_kernel(const float* __restrict__ x,
    const float* __restrict__ rw, const float* __restrict__ rb,
    float* __restrict__ SmT)
{
  const int lane = threadIdx.x & 63;
  const int wid  = threadIdx.x >> 6;
  const int t = blockIdx.x * 4 + wid;     // one token per wave
  const float* xr = x + (size_t)t * HDIM;
  float acc[8] = {0.f,0.f,0.f,0.f,0.f,0.f,0.f,0.f};
#pragma unroll
  for (int it = 0; it < HDIM / 64; ++it) {
    int h = lane + it * 64;
    float xv = xr[h];
    const float4* wp = (const float4*)(rw + h * 8);
    float4 w0 = wp[0], w1 = wp[1];
    acc[0] = fmaf(xv, w0.x, acc[0]);
    acc[1] = fmaf(xv, w0.y, acc[1]);
    acc[2] = fmaf(xv, w0.z, acc[2]);
    acc[3] = fmaf(xv, w0.w, acc[3]);
    acc[4] = fmaf(xv, w1.x, acc[4]);
    acc[5] = fmaf(xv, w1.y, acc[5]);
    acc[6] = fmaf(xv, w1.z, acc[6]);
    acc[7] = fmaf(xv, w1.w, acc[7]);
  }
#pragma unroll
  for (int m = 32; m >= 1; m >>= 1) {
#pragma unroll
    for (int e = 0; e < 8; ++e) acc[e] += __shfl_xor(acc[e], m, 64);
  }
  if (lane == 0) {
    float h[8];
#pragma unroll
    for (int e = 0; e < 8; ++e) {
      uint32_t bits = threefry_bits((uint32_t)(t * 8 + e));
      float u = __uint_as_float((bits >> 9) | 0x3f800000u) - 1.0f;
      u = fmaxf(u, 0.0f);
      float g = -logf(-logf(u + 1e-10f) + 1e-10f);
      h[e] = acc[e] + rb[e] + g;
    }
    float mx = h[0];
#pragma unroll
    for (int e = 1; e < 8; ++e) mx = fmaxf(mx, h[e]);
    float ex[8]; float s = 0.f;
#pragma unroll
    for (int e = 0; e < 8; ++e) { ex[e] = expf(h[e] - mx); s += ex[e]; }
#pragma unroll
    for (int e = 0; e < 8; ++e) SmT[e * N_TOK + t] = ex[e] / s;
  }
}

// ---------------- exact top-1024-of-8192 per expert via 4-pass radix select
// (r5: writes inv[e][tok] = global slot directly -- build_inv fused away)
__global__ __launch_bounds__(1024) void select_topk(const float* __restrict__ SmT,
    uint32_t* __restrict__ selTok, float* __restrict__ selW, int* __restrict__ inv)
{
  const int e = blockIdx.x;
  const int tid = threadIdx.x;
  const float* v = SmT + (size_t)e * N_TOK;
  __shared__ uint32_t hist[256];
  __shared__ uint32_t sh_byte, sh_kk, sh_cnt, sh_eqc;
  uint32_t bitsv[8];
#pragma unroll
  for (int i = 0; i < 8; ++i) bitsv[i] = __float_as_uint(v[tid + i * 1024]);
  uint32_t prefix = 0;
  uint32_t kk = KCAP;
  for (int s = 3; s >= 0; --s) {
    if (tid < 256) hist[tid] = 0;
    __syncthreads();
    uint32_t himask = (s == 3) ? 0u : (0xFFFFFFFFu << ((s + 1) * 8));
#pragma unroll
    for (int i = 0; i < 8; ++i) {
      uint32_t b = bitsv[i];
      if ((b & himask) == prefix) atomicAdd(&hist[(b >> (s * 8)) & 255u], 1u);
    }
    __syncthreads();
    if (tid == 0) {
      uint32_t cum = 0; uint32_t bsel = 0, kn = kk;
      for (int b = 255; b >= 0; --b) {
        uint32_t c = hist[b];
        if (cum + c >= kk) { bsel = (uint32_t)b; kn = kk - cum; break; }
        cum += c;
      }
      sh_byte = bsel; sh_kk = kn;
    }
    __syncthreads();
    prefix |= sh_byte << (s * 8);
    kk = sh_kk;
  }
  const uint32_t T = prefix;
  const uint32_t need = kk;
  if (tid == 0) { sh_cnt = 0; sh_eqc = 0; }
  __syncthreads();
#pragma unroll
  for (int i = 0; i < 8; ++i) {
    uint32_t b = bitsv[i];
    if (b > T) {
      uint32_t p = atomicAdd(&sh_cnt, 1u);
      const uint32_t tok = (uint32_t)(tid + i * 1024);
      selTok[e * KCAP + p] = tok;
      selW[e * KCAP + p] = __uint_as_float(b);
      inv[e * N_TOK + tok] = (int)(e * KCAP + p);
    } else if (b == T) {
      atomicAdd(&sh_eqc, 1u);
    }
  }
  __syncthreads();
  if (sh_eqc == need) {
#pragma unroll
    for (int i = 0; i < 8; ++i) {
      if (bitsv[i] == T) {
        uint32_t p = atomicAdd(&sh_cnt, 1u);
        const uint32_t tok = (uint32_t)(tid + i * 1024);
        selTok[e * KCAP + p] = tok;
        selW[e * KCAP + p] = __uint_as_float(T);
        inv[e * N_TOK + tok] = (int)(e * KCAP + p);
      }
    }
  } else if (tid == 0) {
    uint32_t p = sh_cnt, rem = need;
    for (int t = 0; t < N_TOK && rem > 0u; ++t) {
      if (__float_as_uint(v[t]) == T) {
        selTok[e * KCAP + p] = (uint32_t)t;
        selW[e * KCAP + p] = __uint_as_float(T);
        inv[e * N_TOK + t] = (int)(e * KCAP + p);
        ++p; --rem;
      }
    }
  }
}

// ---------------- gather selected token rows, fp32 -> bf16
__global__ __launch_bounds__(256) void gather_kernel(const float* __restrict__ x,
    const uint32_t* __restrict__ selTok, u16* __restrict__ Xsel)
{
  const int slot = blockIdx.x;
  const int tid = threadIdx.x;
  const uint32_t tok = selTok[slot];
  const float4* src = (const float4*)(x + (size_t)tok * HDIM);
  float4 a = src[tid * 2], b = src[tid * 2 + 1];
  union { u16 h[8]; uint4 vv; } pk;
  pk.h[0] = f2bf(a.x); pk.h[1] = f2bf(a.y); pk.h[2] = f2bf(a.z); pk.h[3] = f2bf(a.w);
  pk.h[4] = f2bf(b.x); pk.h[5] = f2bf(b.y); pk.h[6] = f2bf(b.z); pk.h[7] = f2bf(b.w);
  ((uint4*)(Xsel + (size_t)slot * HDIM))[tid] = pk.vv;
}

// ---------------- transpose + fp32->bf16: out[j][i] = in[i][j], zero-padded
__global__ __launch_bounds__(256) void transpose_convert(const float* __restrict__ in,
    int rows_in, int cols_in, u16* __restrict__ out, int out_cols)
{
  __shared__ float tile[32][33];
  const int bi = blockIdx.y;
  const int bj = blockIdx.x;
  const int tx = threadIdx.x, ty = threadIdx.y;
#pragma unroll
  for (int t = 0; t < 4; ++t) {
    int r = bi * 32 + ty + t * 8, c = bj * 32 + tx;
    float vv = (r < rows_in && c < cols_in) ? in[(size_t)r * cols_in + c] : 0.0f;
    tile[ty + t * 8][tx] = vv;
  }
  __syncthreads();
#pragma unroll
  for (int t = 0; t < 4; ++t) {
    int oj = bj * 32 + ty + t * 8;
    int oi = bi * 32 + tx;
    out[(size_t)oj * out_cols + oi] = f2bf(tile[tx][ty + t * 8]);
  }
}

// ---------------- async global->LDS staging helper
#if defined(__has_builtin)
#  if __has_builtin(__builtin_amdgcn_global_load_lds)
#    define HAVE_GLD 1
#  endif
#endif
#ifdef HAVE_GLD
#define STG(gp, lp) __builtin_amdgcn_global_load_lds( \
    (const __attribute__((address_space(1))) void*)(gp), \
    (__attribute__((address_space(3))) void*)(lp), 16, 0, 0)
#define WAITV6() asm volatile("s_waitcnt vmcnt(6)" ::: "memory")
#define WAITV4() asm volatile("s_waitcnt vmcnt(4)" ::: "memory")
#define WAITV2() asm volatile("s_waitcnt vmcnt(2)" ::: "memory")
#define WAITV0() asm volatile("s_waitcnt vmcnt(0)" ::: "memory")
#else
#define STG(gp, lp) (*(bf16x8*)(lp) = *(const bf16x8*)(gp))
#define WAITV6() asm volatile("s_waitcnt vmcnt(0) lgkmcnt(0)" ::: "memory")
#define WAITV4() asm volatile("s_waitcnt vmcnt(0) lgkmcnt(0)" ::: "memory")
#define WAITV2() asm volatile("s_waitcnt vmcnt(0) lgkmcnt(0)" ::: "memory")
#define WAITV0() asm volatile("s_waitcnt vmcnt(0) lgkmcnt(0)" ::: "memory")
#endif
#define WAITLGKM0() asm volatile("s_waitcnt lgkmcnt(0)" ::: "memory")
#define WAITLGKM8() asm volatile("s_waitcnt lgkmcnt(8)" ::: "memory")
#define BAR()    __builtin_amdgcn_s_barrier()
#define SCHED0() __builtin_amdgcn_sched_barrier(0)
#define PRIO1()  __builtin_amdgcn_s_setprio(1)
#define PRIO0()  __builtin_amdgcn_s_setprio(0)
#define MFMA(a, b, c) __builtin_amdgcn_mfma_f32_16x16x32_bf16(a, b, c, 0, 0, 0)

// ======================================================================
// 3-phase K-loop, TWO-BARRIER phases (r5, m201-faithful), BK=64, 8 waves
// (2M x 4N), 1 block/CU (128 KiB LDS).
// Phase p = { ds_read(operands of p); stage(one half of kt+1);
//             [lgkmcnt(8) if 12 reads]; BAR; lgkmcnt(0); sched_barrier;
//             setprio1; MFMA cluster; setprio0; vmcnt(counted); BAR }
// Mid-phase barrier separates issue from consume: all waves' ds_reads are
// issued before any wave enters MFMA, so barrier-wait absorbs LDS latency.
// Consumption per tile: {A0,B0}@P0, {B1}@P1, {A1}@P2. Staging of kt+1:
// P0: A0'(2 loads/thr); P1: B0'+B1'(4); P2: A1'(2).
// Counted vmcnt at phase END before closing barrier (wait+barrier ==
// all-waves landed): steady endP0 vmcnt(4) lands B1(kt); endP1 vmcnt(6)
// lands A1(kt); endP2 vmcnt(4) lands A0,B0(kt+1). Tail (st==0): endP0
// vmcnt(2), endP1 vmcnt(0) (round-2 lesson: without it the last tile's
// late halves are read un-landed).
// Swizzle: 16B chunk q of row r holds global chunk q^(r&7); frag rows
// == fr (mod 8) -> ds_read_b128 conflict-free. WAR re-stage hazards are
// >= 5 barriers apart (reads of a buffer drain at their phase's
// lgkmcnt(0), its re-stage is 2 tiles later).
// ======================================================================

// GEMM1: act = silu(Xsel*WgT + bg) .* (Xsel*WuT + bu), bf16 out.
// Dual-B: Bg is "B0", Bu is "B1". Block tile 256M x 128N.
// XCD mapping: xcd owns 4 bm values, bn sweeps fastest => A slice (4 MB)
// L2-resident (r4: FETCH 748->275 MB verified).
__global__ __launch_bounds__(512, 2) void gemm1_kernel(
    const u16* __restrict__ Xsel,  // [8192][2048] bf16
    const u16* __restrict__ WgT,   // [5504][2048] bf16 (N-major, K-contig)
    const u16* __restrict__ WuT,   // [5504][2048]
    const float* __restrict__ bg, const float* __restrict__ bu,
    u16* __restrict__ act)         // [8192][5504] bf16
{
  __shared__ u16 AL[2][2][8192];   // 64 KB  (dbuf x Mhalf x 128rows x 64K)
  __shared__ u16 GL[2][8192];      // 32 KB
  __shared__ u16 UL[2][8192];      // 32 KB

  const int id = blockIdx.x;                   // 1376 = 8 * 172
  const int xcd = id & 7;
  const int r = id >> 3;                       // 0..171
  const int bm = xcd * 4 + (r & 3);            // 4 bm per XCD (A L2-resident)
  const int bn = r >> 2;                       // 0..42, sweeps fastest

  const int tid = threadIdx.x;
  const int lane = tid & 63, wid = tid >> 6;
  const int wm = wid >> 2, wn = wid & 3;
  const int fr = lane & 15, ck = lane >> 4;
  const int sw0 = (ck ^ (fr & 7)) * 8;         // u16 offset of ks=0 chunk
  const int sw1 = sw0 ^ 32;                    // ks=1 chunk (^4 chunks)
  const int rA = (wm * 64 + fr) * 64;
  const int rB = (wn * 32 + fr) * 64;

  // staging: thread covers LDS 16B-slots {tid, tid+512} -> rows sr, sr+64,
  // both at swizzled global chunk sq (since 64 ≡ 0 mod 8).
  const int sr = tid >> 3;
  const int sq = (tid & 7) ^ (sr & 7);
  const u16* aS0 = Xsel + (size_t)(bm * 256 + sr) * HDIM + sq * 8;
  const u16* aS1 = aS0 + (size_t)128 * HDIM;
  const u16* gS  = WgT + (size_t)(bn * 128 + sr) * HDIM + sq * 8;
  const u16* uS  = WuT + (size_t)(bn * 128 + sr) * HDIM + sq * 8;

#define ST_A0(kt) { u16* d = &AL[(kt)&1][0][tid*8]; \
    STG(aS0 + (kt)*64, d); STG(aS0 + (kt)*64 + (size_t)64*HDIM, d + 4096); }
#define ST_A1(kt) { u16* d = &AL[(kt)&1][1][tid*8]; \
    STG(aS1 + (kt)*64, d); STG(aS1 + (kt)*64 + (size_t)64*HDIM, d + 4096); }
#define ST_G(kt) { u16* d = &GL[(kt)&1][tid*8]; \
    STG(gS + (kt)*64, d); STG(gS + (kt)*64 + (size_t)64*HDIM, d + 4096); }
#define ST_U(kt) { u16* d = &UL[(kt)&1][tid*8]; \
    STG(uS + (kt)*64, d); STG(uS + (kt)*64 + (size_t)64*HDIM, d + 4096); }

  f32x4 accg[8][2], accu[8][2];
  const f32x4 z4 = {0.f, 0.f, 0.f, 0.f};
#pragma unroll
  for (int i = 0; i < 8; ++i)
#pragma unroll
    for (int n = 0; n < 2; ++n) { accg[i][n] = z4; accu[i][n] = z4; }

  bf16x8 af[4][2], bgf[2][2], buf[2][2];

  // prologue: stage tile0 in issue order A0,G,U,A1; A0+G landed after wait.
  ST_A0(0) ST_G(0) ST_U(0) ST_A1(0)
  WAITV4(); BAR(); SCHED0();

  for (int kt = 0; kt < NT1; ++kt) {
    const u16* A0 = AL[kt & 1][0];
    const u16* A1 = AL[kt & 1][1];
    const u16* G  = GL[kt & 1];
    const u16* U  = UL[kt & 1];
    const int st = (kt + 1 < NT1);
    // ---- P0: read A0 + Bg (12); stage A0'; MFMA accg[0-3] (16)
#pragma unroll
    for (int i = 0; i < 4; ++i) {
      af[i][0] = *(const bf16x8*)&A0[rA + i * 1024 + sw0];
      af[i][1] = *(const bf16x8*)&A0[rA + i * 1024 + sw1];
    }
#pragma unroll
    for (int n = 0; n < 2; ++n) {
      bgf[n][0] = *(const bf16x8*)&G[rB + n * 1024 + sw0];
      bgf[n][1] = *(const bf16x8*)&G[rB + n * 1024 + sw1];
    }
    if (st) ST_A0(kt + 1)
    WAITLGKM8();
    BAR();
    WAITLGKM0(); SCHED0();
    PRIO1();
#pragma unroll
    for (int ks = 0; ks < 2; ++ks)
#pragma unroll
      for (int i = 0; i < 4; ++i)
#pragma unroll
        for (int n = 0; n < 2; ++n)
          accg[i][n] = MFMA(af[i][ks], bgf[n][ks], accg[i][n]);
    PRIO0();
    if (st) { WAITV4(); } else { WAITV2(); }
    BAR(); SCHED0();
    // ---- P1: read Bu (4); stage G'+U'; MFMA accu[0-3] (16)
#pragma unroll
    for (int n = 0; n < 2; ++n) {
      buf[n][0] = *(const bf16x8*)&U[rB + n * 1024 + sw0];
      buf[n][1] = *(const bf16x8*)&U[rB + n * 1024 + sw1];
    }
    if (st) { ST_G(kt + 1) ST_U(kt + 1) }
    BAR();
    WAITLGKM0(); SCHED0();
    PRIO1();
#pragma unroll
    for (int ks = 0; ks < 2; ++ks)
#pragma unroll
      for (int i = 0; i < 4; ++i)
#pragma unroll
        for (int n = 0; n < 2; ++n)
          accu[i][n] = MFMA(af[i][ks], buf[n][ks], accu[i][n]);
    PRIO0();
    if (st) { WAITV6(); } else { WAITV0(); }
    BAR(); SCHED0();
    // ---- P2: read A1 (8); stage A1'; MFMA accg[4-7]+accu[4-7] (32)
#pragma unroll
    for (int i = 0; i < 4; ++i) {
      af[i][0] = *(const bf16x8*)&A1[rA + i * 1024 + sw0];
      af[i][1] = *(const bf16x8*)&A1[rA + i * 1024 + sw1];
    }
    if (st) ST_A1(kt + 1)
    BAR();
    WAITLGKM0(); SCHED0();
    PRIO1();
#pragma unroll
    for (int ks = 0; ks < 2; ++ks)
#pragma unroll
      for (int i = 0; i < 4; ++i)
#pragma unroll
        for (int n = 0; n < 2; ++n) {
          accg[4 + i][n] = MFMA(af[i][ks], bgf[n][ks], accg[4 + i][n]);
          accu[4 + i][n] = MFMA(af[i][ks], buf[n][ks], accu[4 + i][n]);
        }
    PRIO0();
    WAITV4();
    BAR(); SCHED0();
  }

  // epilogue: silu(g+bg)*(u+bu) -> bf16; pad cols [DFF, ACT_P) get 0.
#pragma unroll
  for (int f = 0; f < 8; ++f) {
    const int rbase = bm * 256 + (f >> 2) * 128 + wm * 64 + (f & 3) * 16 + ck * 4;
#pragma unroll
    for (int v = 0; v < 4; ++v) {
      u16* arow = act + (size_t)(rbase + v) * ACT_P;
#pragma unroll
      for (int n = 0; n < 2; ++n) {
        const int col = bn * 128 + wn * 32 + n * 16 + fr;
        u16 ov = 0;
        if (col < DFF) {
          float gv = accg[f][n][v] + bg[col];
          float uv = accu[f][n][v] + bu[col];
          float e = __expf(-gv);
          float sv = gv * __builtin_amdgcn_rcpf(1.0f + e);
          ov = f2bf(sv * uv);
        }
        arow[col] = ov;
      }
    }
  }
#undef ST_A0
#undef ST_A1
#undef ST_G
#undef ST_U
}

// GEMM2: Yslot[slot] = selW[slot] * (act[slot]*WdT + bd)  (dense, no atomics)
// Block tile 256M x 256N, wave tile 128M x 64N. Grid 32bm x 8bn = 256 = 8*32.
__global__ __launch_bounds__(512, 2) void gemm2_kernel(
    const u16* __restrict__ act,   // [8192][5504] bf16
    const u16* __restrict__ WdT,   // [2048][5504] bf16
    const float* __restrict__ bd,  // [2048]
    const float* __restrict__ selW,
    float* __restrict__ Yslot)     // [8192][2048] fp32 slot-major
{
  __shared__ u16 AL[2][2][8192];   // 64 KB
  __shared__ u16 BL[2][2][8192];   // 64 KB

  const int id = blockIdx.x;                  // 256 = 8 * 32
  const int wg = (id & 7) * 32 + (id >> 3);
  const int bm = wg & 31, bn = wg >> 5;

  const int tid = threadIdx.x;
  const int lane = tid & 63, wid = tid >> 6;
  const int wm = wid >> 2, wn = wid & 3;
  const int fr = lane & 15, ck = lane >> 4;
  const int sw0 = (ck ^ (fr & 7)) * 8;
  const int sw1 = sw0 ^ 32;
  const int rA = (wm * 64 + fr) * 64;
  const int rB = (wn * 32 + fr) * 64;

  const int sr = tid >> 3;
  const int sq = (tid & 7) ^ (sr & 7);
  const u16* aS0 = act + (size_t)(bm * 256 + sr) * ACT_P + sq * 8;
  const u16* aS1 = aS0 + (size_t)128 * ACT_P;
  const u16* bS0 = WdT + (size_t)(bn * 256 + sr) * ACT_P + sq * 8;
  const u16* bS1 = bS0 + (size_t)128 * ACT_P;

#define ST_A0(kt) { u16* d = &AL[(kt)&1][0][tid*8]; \
    STG(aS0 + (kt)*64, d); STG(aS0 + (kt)*64 + (size_t)64*ACT_P, d + 4096); }
#define ST_A1(kt) { u16* d = &AL[(kt)&1][1][tid*8]; \
    STG(aS1 + (kt)*64, d); STG(aS1 + (kt)*64 + (size_t)64*ACT_P, d + 4096); }
#define ST_B0(kt) { u16* d = &BL[(kt)&1][0][tid*8]; \
    STG(bS0 + (kt)*64, d); STG(bS0 + (kt)*64 + (size_t)64*ACT_P, d + 4096); }
#define ST_B1(kt) { u16* d = &BL[(kt)&1][1][tid*8]; \
    STG(bS1 + (kt)*64, d); STG(bS1 + (kt)*64 + (size_t)64*ACT_P, d + 4096); }

  f32x4 acc[8][4];
  const f32x4 z4 = {0.f, 0.f, 0.f, 0.f};
#pragma unroll
  for (int i = 0; i < 8; ++i)
#pragma unroll
    for (int n = 0; n < 4; ++n) acc[i][n] = z4;

  bf16x8 af[4][2], b0[2][2], b1[2][2];

  ST_A0(0) ST_B0(0) ST_B1(0) ST_A1(0)
  WAITV4(); BAR(); SCHED0();

  for (int kt = 0; kt < NT2; ++kt) {
    const u16* A0 = AL[kt & 1][0];
    const u16* A1 = AL[kt & 1][1];
    const u16* B0 = BL[kt & 1][0];
    const u16* B1 = BL[kt & 1][1];
    const int st = (kt + 1 < NT2);
    // ---- P0: read A0 + B0 (12); stage A0'; MFMA acc[0-3][0-1] (16)
#pragma unroll
    for (int i = 0; i < 4; ++i) {
      af[i][0] = *(const bf16x8*)&A0[rA + i * 1024 + sw0];
      af[i][1] = *(const bf16x8*)&A0[rA + i * 1024 + sw1];
    }
#pragma unroll
    for (int n = 0; n < 2; ++n) {
      b0[n][0] = *(const bf16x8*)&B0[rB + n * 1024 + sw0];
      b0[n][1] = *(const bf16x8*)&B0[rB + n * 1024 + sw1];
    }
    if (st) ST_A0(kt + 1)
    WAITLGKM8();
    BAR();
    WAITLGKM0(); SCHED0();
    PRIO1();
#pragma unroll
    for (int ks = 0; ks < 2; ++ks)
#pragma unroll
      for (int i = 0; i < 4; ++i)
#pragma unroll
        for (int n = 0; n < 2; ++n)
          acc[i][n] = MFMA(af[i][ks], b0[n][ks], acc[i][n]);
    PRIO0();
    if (st) { WAITV4(); } else { WAITV2(); }
    BAR(); SCHED0();
    // ---- P1: read B1 (4); stage B0'+B1'; MFMA acc[0-3][2-3] (16)
#pragma unroll
    for (int n = 0; n < 2; ++n) {
      b1[n][0] = *(const bf16x8*)&B1[rB + n * 1024 + sw0];
      b1[n][1] = *(const bf16x8*)&B1[rB + n * 1024 + sw1];
    }
    if (st) { ST_B0(kt + 1) ST_B1(kt + 1) }
    BAR();
    WAITLGKM0(); SCHED0();
    PRIO1();
#pragma unroll
    for (int ks = 0; ks < 2; ++ks)
#pragma unroll
      for (int i = 0; i < 4; ++i)
#pragma unroll
        for (int n = 0; n < 2; ++n)
          acc[i][2 + n] = MFMA(af[i][ks], b1[n][ks], acc[i][2 + n]);
    PRIO0();
    if (st) { WAITV6(); } else { WAITV0(); }
    BAR(); SCHED0();
    // ---- P2: read A1 (8); stage A1'; MFMA acc[4-7][0-3] (32)
#pragma unroll
    for (int i = 0; i < 4; ++i) {
      af[i][0] = *(const bf16x8*)&A1[rA + i * 1024 + sw0];
      af[i][1] = *(const bf16x8*)&A1[rA + i * 1024 + sw1];
    }
    if (st) ST_A1(kt + 1)
    BAR();
    WAITLGKM0(); SCHED0();
    PRIO1();
#pragma unroll
    for (int ks = 0; ks < 2; ++ks)
#pragma unroll
      for (int i = 0; i < 4; ++i)
#pragma unroll
        for (int n = 0; n < 2; ++n) {
          acc[4 + i][n]     = MFMA(af[i][ks], b0[n][ks], acc[4 + i][n]);
          acc[4 + i][2 + n] = MFMA(af[i][ks], b1[n][ks], acc[4 + i][2 + n]);
        }
    PRIO0();
    WAITV4();
    BAR(); SCHED0();
  }

  // epilogue: weighted dense store (no atomics)
#pragma unroll
  for (int f = 0; f < 8; ++f) {
    const int rbase = bm * 256 + (f >> 2) * 128 + wm * 64 + (f & 3) * 16 + ck * 4;
#pragma unroll
    for (int v = 0; v < 4; ++v) {
      const int srow = rbase + v;
      const float w = selW[srow];
      float* yrow = Yslot + (size_t)srow * HDIM;
#pragma unroll
      for (int n = 0; n < 4; ++n) {
        const int col = bn * 256 + (n >> 1) * 128 + wn * 32 + (n & 1) * 16 + fr;
        yrow[col] = w * (acc[f][n][v] + bd[col]);
      }
    }
  }
#undef ST_A0
#undef ST_A1
#undef ST_B0
#undef ST_B1
}

// ---------------- scatter: y[tok] = sum over experts of Yslot[inv[e][tok]]
__global__ __launch_bounds__(256) void scatter_kernel(const float* __restrict__ Yslot,
    const int* __restrict__ inv, float* __restrict__ y)
{
  const int t = blockIdx.x;
  const int c = threadIdx.x * 8;
  float4 a0 = {0.f,0.f,0.f,0.f}, a1 = {0.f,0.f,0.f,0.f};
#pragma unroll
  for (int e = 0; e < 8; ++e) {
    const int s = inv[e * N_TOK + t];
    if (s >= 0) {
      const float4* p = (const float4*)(Yslot + (size_t)s * HDIM + c);
      float4 v0 = p[0], v1 = p[1];
      a0.x += v0.x; a0.y += v0.y; a0.z += v0.z; a0.w += v0.w;
      a1.x += v1.x; a1.y += v1.y; a1.z += v1.z; a1.w += v1.w;
    }
  }
  float4* yp = (float4*)(y + (size_t)t * HDIM + c);
  yp[0] = a0; yp[1] = a1;
}

extern "C" void kernel_launch(void* const* d_in, const int* in_sizes, int n_in,
                              void* d_out, int out_size, void* d_ws, size_t ws_size,
                              hipStream_t stream) {
  const float* x      = (const float*)d_in[0];
  const float* rw     = (const float*)d_in[1];
  const float* rb     = (const float*)d_in[2];
  const float* w_gate = (const float*)d_in[3];
  const float* b_gate = (const float*)d_in[4];
  const float* w_up   = (const float*)d_in[5];
  const float* b_up   = (const float*)d_in[6];
  const float* w_down = (const float*)d_in[7];
  const float* b_down = (const float*)d_in[8];
  float* y = (float*)d_out;

  // Workspace layout (max end 180,158,464 B; aliasing by lifetime):
  //  [0,32K)        selTok ; [32K,64K) selW ; [64K,320K) inv
  //  [320K,90.5M)   act [8192][5504] bf16 (gemm1 -> gemm2)
  //  [90.5M,124.06M) Xsel (gather->gemm1); WdT aliases (post-gemm1)
  //  [113.05M,180.2M) Yslot f32 (gemm2->scatter); overlays SmT/WgT/WuT
  //  [124.06M,124.3M) SmT ; [124.3M,146.9M) WgT ; [146.9M,169.4M) WuT
  uint8_t* ws = (uint8_t*)d_ws;
  uint32_t* selTok = (uint32_t*)(ws + 0);
  float*    selW   = (float*)(ws + 32768);
  int*      inv    = (int*)(ws + 65536);
  u16*      act    = (u16*)(ws + 327680);
  u16*      Xsel   = (u16*)(ws + 90505216ull);
  u16*      WdT    = (u16*)(ws + 90505216ull);
  float*    Yslot  = (float*)(ws + 113049600ull);
  float*    SmT    = (float*)(ws + 124059648ull);
  u16*      WgT    = (u16*)(ws + 124321792ull);
  u16*      WuT    = (u16*)(ws + 146866176ull);

  hipMemsetAsync(inv, 0xFF, NEXP * N_TOK * sizeof(int), stream);
  transpose_convert<<<dim3(172, 64), dim3(32, 8), 0, stream>>>(w_gate, 2048, DFF, WgT, 2048);
  transpose_convert<<<dim3(172, 64), dim3(32, 8), 0, stream>>>(w_up,   2048, DFF, WuT, 2048);
  router_kernel<<<N_TOK / 4, 256, 0, stream>>>(x, rw, rb, SmT);
  select_topk<<<NEXP, 1024, 0, stream>>>(SmT, selTok, selW, inv);
  gather_kernel<<<N_TOK, 256, 0, stream>>>(x, selTok, Xsel);
  gemm1_kernel<<<43 * 32, 512, 0, stream>>>(Xsel, WgT, WuT, b_gate, b_up, act);
  transpose_convert<<<dim3(64, 172), dim3(32, 8), 0, stream>>>(w_down, DFF, 2048, WdT, ACT_P);
  gemm2_kernel<<<8 * 32, 512, 0, stream>>>(act, WdT, b_down, selW, Yslot);
  scatter_kernel<<<N_TOK, 256, 0, stream>>>(Yslot, inv, y);
}

// Round 6
// 867.428 us; speedup vs baseline: 1.0276x; 1.0276x over previous
//
#include <hip/hip_runtime.h>
#include <cstdint>
#include <cstddef>

#define N_TOK  8192
#define HDIM   2048
#define NEXP   8
#define KCAP   1024
#define DFF    5461
#define DFF_PB 5504   // padded rows for WgT/WuT (N of gemm1)
#define ACT_P  5504   // act row pitch / gemm2 K (multiple of 64)
#define NT1    (HDIM / 64)    // 32
#define NT2    (ACT_P / 64)   // 86

typedef unsigned short u16;
typedef short bf16x8 __attribute__((ext_vector_type(8)));
typedef float f32x4  __attribute__((ext_vector_type(4)));

__device__ __forceinline__ u16 f2bf(float f) {
  uint32_t u = __float_as_uint(f);
  uint32_t r = (u + 0x7FFFu + ((u >> 16) & 1u)) >> 16;
  return (u16)r;
}

__device__ __forceinline__ uint32_t rotl32(uint32_t v, int d) {
  return (v << d) | (v >> (32 - d));
}

// JAX threefry2x32, key = (0, 42), partitionable scheme: counter=(0,i), bits = x0^x1.
__device__ uint32_t threefry_bits(uint32_t idx) {
  const uint32_t ks0 = 0u, ks1 = 42u, ks2 = 0u ^ 42u ^ 0x1BD11BDAu;
  uint32_t x0 = 0u + ks0;
  uint32_t x1 = idx + ks1;
#define TFR(d) { x0 += x1; x1 = rotl32(x1, d); x1 ^= x0; }
  TFR(13) TFR(15) TFR(26) TFR(6)
  x0 += ks1; x1 += ks2 + 1u;
  TFR(17) TFR(29) TFR(16) TFR(24)
  x0 += ks2; x1 += ks0 + 2u;
  TFR(13) TFR(15) TFR(26) TFR(6)
  x0 += ks0; x1 += ks1 + 3u;
  TFR(17) TFR(29) TFR(16) TFR(24)
  x0 += ks1; x1 += ks2 + 4u;
  TFR(13) TFR(15) TFR(26) TFR(6)
  x0 += ks2; x1 += ks0 + 5u;
#undef TFR
  return x0 ^ x1;
}

// ---------------- router: clean_h + gumbel -> softmax, stored transposed [E][n_tok]
__global__ __launch_bounds__(256) void router_kernel(const float* __restrict__ x,
    const float* __restrict__ rw, const float* __restrict__ rb,
    float* __restrict__ SmT)
{
  const int lane = threadIdx.x & 63;
  const int wid  = threadIdx.x >> 6;
  const int t = blockIdx.x * 4 + wid;     // one token per wave
  const float* xr = x + (size_t)t * HDIM;
  float acc[8] = {0.f,0.f,0.f,0.f,0.f,0.f,0.f,0.f};
#pragma unroll
  for (int it = 0; it < HDIM / 64; ++it) {
    int h = lane + it * 64;
    float xv = xr[h];
    const float4* wp = (const float4*)(rw + h * 8);
    float4 w0 = wp[0], w1 = wp[1];
    acc[0] = fmaf(xv, w0.x, acc[0]);
    acc[1] = fmaf(xv, w0.y, acc[1]);
    acc[2] = fmaf(xv, w0.z, acc[2]);
    acc[3] = fmaf(xv, w0.w, acc[3]);
    acc[4] = fmaf(xv, w1.x, acc[4]);
    acc[5] = fmaf(xv, w1.y, acc[5]);
    acc[6] = fmaf(xv, w1.z, acc[6]);
    acc[7] = fmaf(xv, w1.w, acc[7]);
  }
#pragma unroll
  for (int m = 32; m >= 1; m >>= 1) {
#pragma unroll
    for (int e = 0; e < 8; ++e) acc[e] += __shfl_xor(acc[e], m, 64);
  }
  if (lane == 0) {
    float h[8];
#pragma unroll
    for (int e = 0; e < 8; ++e) {
      uint32_t bits = threefry_bits((uint32_t)(t * 8 + e));
      float u = __uint_as_float((bits >> 9) | 0x3f800000u) - 1.0f;
      u = fmaxf(u, 0.0f);
      float g = -logf(-logf(u + 1e-10f) + 1e-10f);
      h[e] = acc[e] + rb[e] + g;
    }
    float mx = h[0];
#pragma unroll
    for (int e = 1; e < 8; ++e) mx = fmaxf(mx, h[e]);
    float ex[8]; float s = 0.f;
#pragma unroll
    for (int e = 0; e < 8; ++e) { ex[e] = expf(h[e] - mx); s += ex[e]; }
#pragma unroll
    for (int e = 0; e < 8; ++e) SmT[e * N_TOK + t] = ex[e] / s;
  }
}

// ---------------- exact top-1024-of-8192 per expert via 4-pass radix select
// (writes inv[e][tok] = global slot directly -- build_inv fused)
__global__ __launch_bounds__(1024) void select_topk(const float* __restrict__ SmT,
    uint32_t* __restrict__ selTok, float* __restrict__ selW, int* __restrict__ inv)
{
  const int e = blockIdx.x;
  const int tid = threadIdx.x;
  const float* v = SmT + (size_t)e * N_TOK;
  __shared__ uint32_t hist[256];
  __shared__ uint32_t sh_byte, sh_kk, sh_cnt, sh_eqc;
  uint32_t bitsv[8];
#pragma unroll
  for (int i = 0; i < 8; ++i) bitsv[i] = __float_as_uint(v[tid + i * 1024]);
  uint32_t prefix = 0;
  uint32_t kk = KCAP;
  for (int s = 3; s >= 0; --s) {
    if (tid < 256) hist[tid] = 0;
    __syncthreads();
    uint32_t himask = (s == 3) ? 0u : (0xFFFFFFFFu << ((s + 1) * 8));
#pragma unroll
    for (int i = 0; i < 8; ++i) {
      uint32_t b = bitsv[i];
      if ((b & himask) == prefix) atomicAdd(&hist[(b >> (s * 8)) & 255u], 1u);
    }
    __syncthreads();
    if (tid == 0) {
      uint32_t cum = 0; uint32_t bsel = 0, kn = kk;
      for (int b = 255; b >= 0; --b) {
        uint32_t c = hist[b];
        if (cum + c >= kk) { bsel = (uint32_t)b; kn = kk - cum; break; }
        cum += c;
      }
      sh_byte = bsel; sh_kk = kn;
    }
    __syncthreads();
    prefix |= sh_byte << (s * 8);
    kk = sh_kk;
  }
  const uint32_t T = prefix;
  const uint32_t need = kk;
  if (tid == 0) { sh_cnt = 0; sh_eqc = 0; }
  __syncthreads();
#pragma unroll
  for (int i = 0; i < 8; ++i) {
    uint32_t b = bitsv[i];
    if (b > T) {
      uint32_t p = atomicAdd(&sh_cnt, 1u);
      const uint32_t tok = (uint32_t)(tid + i * 1024);
      selTok[e * KCAP + p] = tok;
      selW[e * KCAP + p] = __uint_as_float(b);
      inv[e * N_TOK + tok] = (int)(e * KCAP + p);
    } else if (b == T) {
      atomicAdd(&sh_eqc, 1u);
    }
  }
  __syncthreads();
  if (sh_eqc == need) {
#pragma unroll
    for (int i = 0; i < 8; ++i) {
      if (bitsv[i] == T) {
        uint32_t p = atomicAdd(&sh_cnt, 1u);
        const uint32_t tok = (uint32_t)(tid + i * 1024);
        selTok[e * KCAP + p] = tok;
        selW[e * KCAP + p] = __uint_as_float(T);
        inv[e * N_TOK + tok] = (int)(e * KCAP + p);
      }
    }
  } else if (tid == 0) {
    uint32_t p = sh_cnt, rem = need;
    for (int t = 0; t < N_TOK && rem > 0u; ++t) {
      if (__float_as_uint(v[t]) == T) {
        selTok[e * KCAP + p] = (uint32_t)t;
        selW[e * KCAP + p] = __uint_as_float(T);
        inv[e * N_TOK + t] = (int)(e * KCAP + p);
        ++p; --rem;
      }
    }
  }
}

// ---------------- gather selected token rows, fp32 -> bf16
__global__ __launch_bounds__(256) void gather_kernel(const float* __restrict__ x,
    const uint32_t* __restrict__ selTok, u16* __restrict__ Xsel)
{
  const int slot = blockIdx.x;
  const int tid = threadIdx.x;
  const uint32_t tok = selTok[slot];
  const float4* src = (const float4*)(x + (size_t)tok * HDIM);
  float4 a = src[tid * 2], b = src[tid * 2 + 1];
  union { u16 h[8]; uint4 vv; } pk;
  pk.h[0] = f2bf(a.x); pk.h[1] = f2bf(a.y); pk.h[2] = f2bf(a.z); pk.h[3] = f2bf(a.w);
  pk.h[4] = f2bf(b.x); pk.h[5] = f2bf(b.y); pk.h[6] = f2bf(b.z); pk.h[7] = f2bf(b.w);
  ((uint4*)(Xsel + (size_t)slot * HDIM))[tid] = pk.vv;
}

// ---------------- transpose + fp32->bf16: out[j][i] = in[i][j], zero-padded
__global__ __launch_bounds__(256) void transpose_convert(const float* __restrict__ in,
    int rows_in, int cols_in, u16* __restrict__ out, int out_cols)
{
  __shared__ float tile[32][33];
  const int bi = blockIdx.y;
  const int bj = blockIdx.x;
  const int tx = threadIdx.x, ty = threadIdx.y;
#pragma unroll
  for (int t = 0; t < 4; ++t) {
    int r = bi * 32 + ty + t * 8, c = bj * 32 + tx;
    float vv = (r < rows_in && c < cols_in) ? in[(size_t)r * cols_in + c] : 0.0f;
    tile[ty + t * 8][tx] = vv;
  }
  __syncthreads();
#pragma unroll
  for (int t = 0; t < 4; ++t) {
    int oj = bj * 32 + ty + t * 8;
    int oi = bi * 32 + tx;
    out[(size_t)oj * out_cols + oi] = f2bf(tile[tx][ty + t * 8]);
  }
}

// ---------------- batched transpose for w_gate + w_up (z selects matrix)
__global__ __launch_bounds__(256) void transpose_convert_gu(
    const float* __restrict__ g, const float* __restrict__ u,
    u16* __restrict__ og, u16* __restrict__ ou)
{
  const float* in = blockIdx.z ? u : g;
  u16* out = blockIdx.z ? ou : og;
  __shared__ float tile[32][33];
  const int bi = blockIdx.y;
  const int bj = blockIdx.x;
  const int tx = threadIdx.x, ty = threadIdx.y;
#pragma unroll
  for (int t = 0; t < 4; ++t) {
    int r = bi * 32 + ty + t * 8, c = bj * 32 + tx;
    float vv = (r < 2048 && c < DFF) ? in[(size_t)r * DFF + c] : 0.0f;
    tile[ty + t * 8][tx] = vv;
  }
  __syncthreads();
#pragma unroll
  for (int t = 0; t < 4; ++t) {
    int oj = bj * 32 + ty + t * 8;
    int oi = bi * 32 + tx;
    out[(size_t)oj * 2048 + oi] = f2bf(tile[tx][ty + t * 8]);
  }
}

// ---------------- async global->LDS staging helper
#if defined(__has_builtin)
#  if __has_builtin(__builtin_amdgcn_global_load_lds)
#    define HAVE_GLD 1
#  endif
#endif
#ifdef HAVE_GLD
#define STG(gp, lp) __builtin_amdgcn_global_load_lds( \
    (const __attribute__((address_space(1))) void*)(gp), \
    (__attribute__((address_space(3))) void*)(lp), 16, 0, 0)
#define WAITV6() asm volatile("s_waitcnt vmcnt(6)" ::: "memory")
#define WAITV4() asm volatile("s_waitcnt vmcnt(4)" ::: "memory")
#define WAITV2() asm volatile("s_waitcnt vmcnt(2)" ::: "memory")
#define WAITV0() asm volatile("s_waitcnt vmcnt(0)" ::: "memory")
#else
#define STG(gp, lp) (*(bf16x8*)(lp) = *(const bf16x8*)(gp))
#define WAITV6() asm volatile("s_waitcnt vmcnt(0) lgkmcnt(0)" ::: "memory")
#define WAITV4() asm volatile("s_waitcnt vmcnt(0) lgkmcnt(0)" ::: "memory")
#define WAITV2() asm volatile("s_waitcnt vmcnt(0) lgkmcnt(0)" ::: "memory")
#define WAITV0() asm volatile("s_waitcnt vmcnt(0) lgkmcnt(0)" ::: "memory")
#endif
#define BAR()    __builtin_amdgcn_s_barrier()
#define SCHED0() __builtin_amdgcn_sched_barrier(0)
#define PRIO1()  __builtin_amdgcn_s_setprio(1)
#define PRIO0()  __builtin_amdgcn_s_setprio(0)
#define MFMA(a, b, c) __builtin_amdgcn_mfma_f32_16x16x32_bf16(a, b, c, 0, 0, 0)

// ======================================================================
// 3-phase K-loop (r4-verified best), BK=64, 8 waves (2M x 4N), 1 block/CU
// (128 KiB LDS). Consumption per tile: {A0,B0}@P0, {B1}@P1, {A1}@P2.
// Staging of kt+1: P0: A0' (2 loads/thr); P1: B0'+B1' (4); P2: A1' (2).
// Waits at phase END before the barrier (per-wave vmcnt + barrier ==
// all-waves landed). Steady state: endP0 vmcnt(4) lands B1(kt); endP1
// vmcnt(6) lands A1(kt); endP2 vmcnt(4) lands A0,B0(kt+1). Tail (st==0,
// nothing staged): endP0 vmcnt(2), endP1 vmcnt(0) (round-2 lesson).
// ONE barrier per phase: r5's m201-style mid-phase barrier REGRESSED
// (408->428 us) -- do not reintroduce. Swizzle: 16B chunk q of row r
// holds global chunk q^(r&7); frag rows == fr (mod 8) ->
// ds_read_b128 conflict-free (SQ_LDS_BANK_CONFLICT == 0 measured).
// ======================================================================

// GEMM1: act = silu(Xsel*WgT + bg) .* (Xsel*WuT + bu), bf16 out.
// Dual-B: Bg is "B0", Bu is "B1". Block tile 256M x 128N.
// XCD mapping: xcd owns 4 bm values, bn sweeps fastest => A slice (4 MB)
// L2-resident (FETCH 748->275 MB verified in r4).
__global__ __launch_bounds__(512, 2) void gemm1_kernel(
    const u16* __restrict__ Xsel,  // [8192][2048] bf16
    const u16* __restrict__ WgT,   // [5504][2048] bf16 (N-major, K-contig)
    const u16* __restrict__ WuT,   // [5504][2048]
    const float* __restrict__ bg, const float* __restrict__ bu,
    u16* __restrict__ act)         // [8192][5504] bf16
{
  __shared__ u16 AL[2][2][8192];   // 64 KB  (dbuf x Mhalf x 128rows x 64K)
  __shared__ u16 GL[2][8192];      // 32 KB
  __shared__ u16 UL[2][8192];      // 32 KB

  const int id = blockIdx.x;                   // 1376 = 8 * 172
  const int xcd = id & 7;
  const int r = id >> 3;                       // 0..171
  const int bm = xcd * 4 + (r & 3);            // 4 bm per XCD (A L2-resident)
  const int bn = r >> 2;                       // 0..42, sweeps fastest

  const int tid = threadIdx.x;
  const int lane = tid & 63, wid = tid >> 6;
  const int wm = wid >> 2, wn = wid & 3;
  const int fr = lane & 15, ck = lane >> 4;
  const int sw0 = (ck ^ (fr & 7)) * 8;         // u16 offset of ks=0 chunk
  const int sw1 = sw0 ^ 32;                    // ks=1 chunk (^4 chunks)
  const int rA = (wm * 64 + fr) * 64;
  const int rB = (wn * 32 + fr) * 64;

  // staging: thread covers LDS 16B-slots {tid, tid+512} -> rows sr, sr+64,
  // both at swizzled global chunk sq (since 64 ≡ 0 mod 8).
  const int sr = tid >> 3;
  const int sq = (tid & 7) ^ (sr & 7);
  const u16* aS0 = Xsel + (size_t)(bm * 256 + sr) * HDIM + sq * 8;
  const u16* aS1 = aS0 + (size_t)128 * HDIM;
  const u16* gS  = WgT + (size_t)(bn * 128 + sr) * HDIM + sq * 8;
  const u16* uS  = WuT + (size_t)(bn * 128 + sr) * HDIM + sq * 8;

#define ST_A0(kt) { u16* d = &AL[(kt)&1][0][tid*8]; \
    STG(aS0 + (kt)*64, d); STG(aS0 + (kt)*64 + (size_t)64*HDIM, d + 4096); }
#define ST_A1(kt) { u16* d = &AL[(kt)&1][1][tid*8]; \
    STG(aS1 + (kt)*64, d); STG(aS1 + (kt)*64 + (size_t)64*HDIM, d + 4096); }
#define ST_G(kt) { u16* d = &GL[(kt)&1][tid*8]; \
    STG(gS + (kt)*64, d); STG(gS + (kt)*64 + (size_t)64*HDIM, d + 4096); }
#define ST_U(kt) { u16* d = &UL[(kt)&1][tid*8]; \
    STG(uS + (kt)*64, d); STG(uS + (kt)*64 + (size_t)64*HDIM, d + 4096); }

  f32x4 accg[8][2], accu[8][2];
  const f32x4 z4 = {0.f, 0.f, 0.f, 0.f};
#pragma unroll
  for (int i = 0; i < 8; ++i)
#pragma unroll
    for (int n = 0; n < 2; ++n) { accg[i][n] = z4; accu[i][n] = z4; }

  bf16x8 af[4][2], bgf[2][2], buf[2][2];

  // prologue: stage tile0 in issue order A0,G,U,A1; A0+G landed after wait.
  ST_A0(0) ST_G(0) ST_U(0) ST_A1(0)
  WAITV4(); BAR(); SCHED0();

  for (int kt = 0; kt < NT1; ++kt) {
    const u16* A0 = AL[kt & 1][0];
    const u16* A1 = AL[kt & 1][1];
    const u16* G  = GL[kt & 1];
    const u16* U  = UL[kt & 1];
    const int st = (kt + 1 < NT1);
    // ---- P0: read A0 + Bg; stage A0'; MFMA accg[0-3] (16)
#pragma unroll
    for (int i = 0; i < 4; ++i) {
      af[i][0] = *(const bf16x8*)&A0[rA + i * 1024 + sw0];
      af[i][1] = *(const bf16x8*)&A0[rA + i * 1024 + sw1];
    }
#pragma unroll
    for (int n = 0; n < 2; ++n) {
      bgf[n][0] = *(const bf16x8*)&G[rB + n * 1024 + sw0];
      bgf[n][1] = *(const bf16x8*)&G[rB + n * 1024 + sw1];
    }
    if (st) ST_A0(kt + 1)
    PRIO1();
#pragma unroll
    for (int ks = 0; ks < 2; ++ks)
#pragma unroll
      for (int i = 0; i < 4; ++i)
#pragma unroll
        for (int n = 0; n < 2; ++n)
          accg[i][n] = MFMA(af[i][ks], bgf[n][ks], accg[i][n]);
    PRIO0();
    if (st) { WAITV4(); } else { WAITV2(); }
    BAR(); SCHED0();
    // ---- P1: read Bu; stage G'+U'; MFMA accu[0-3] (16)
#pragma unroll
    for (int n = 0; n < 2; ++n) {
      buf[n][0] = *(const bf16x8*)&U[rB + n * 1024 + sw0];
      buf[n][1] = *(const bf16x8*)&U[rB + n * 1024 + sw1];
    }
    if (st) { ST_G(kt + 1) ST_U(kt + 1) }
    PRIO1();
#pragma unroll
    for (int ks = 0; ks < 2; ++ks)
#pragma unroll
      for (int i = 0; i < 4; ++i)
#pragma unroll
        for (int n = 0; n < 2; ++n)
          accu[i][n] = MFMA(af[i][ks], buf[n][ks], accu[i][n]);
    PRIO0();
    if (st) { WAITV6(); } else { WAITV0(); }
    BAR(); SCHED0();
    // ---- P2: read A1; stage A1'; MFMA accg[4-7]+accu[4-7] (32)
#pragma unroll
    for (int i = 0; i < 4; ++i) {
      af[i][0] = *(const bf16x8*)&A1[rA + i * 1024 + sw0];
      af[i][1] = *(const bf16x8*)&A1[rA + i * 1024 + sw1];
    }
    if (st) ST_A1(kt + 1)
    PRIO1();
#pragma unroll
    for (int ks = 0; ks < 2; ++ks)
#pragma unroll
      for (int i = 0; i < 4; ++i)
#pragma unroll
        for (int n = 0; n < 2; ++n) {
          accg[4 + i][n] = MFMA(af[i][ks], bgf[n][ks], accg[4 + i][n]);
          accu[4 + i][n] = MFMA(af[i][ks], buf[n][ks], accu[4 + i][n]);
        }
    PRIO0();
    WAITV4();
    BAR(); SCHED0();
  }

  // epilogue: silu(g+bg)*(u+bu) -> bf16; pad cols [DFF, ACT_P) get 0.
#pragma unroll
  for (int f = 0; f < 8; ++f) {
    const int rbase = bm * 256 + (f >> 2) * 128 + wm * 64 + (f & 3) * 16 + ck * 4;
#pragma unroll
    for (int v = 0; v < 4; ++v) {
      u16* arow = act + (size_t)(rbase + v) * ACT_P;
#pragma unroll
      for (int n = 0; n < 2; ++n) {
        const int col = bn * 128 + wn * 32 + n * 16 + fr;
        u16 ov = 0;
        if (col < DFF) {
          float gv = accg[f][n][v] + bg[col];
          float uv = accu[f][n][v] + bu[col];
          float e = __expf(-gv);
          float sv = gv * __builtin_amdgcn_rcpf(1.0f + e);
          ov = f2bf(sv * uv);
        }
        arow[col] = ov;
      }
    }
  }
#undef ST_A0
#undef ST_A1
#undef ST_G
#undef ST_U
}

// GEMM2: Yslot[slot] = selW[slot] * (act[slot]*WdT + bd)  (dense, no atomics)
// Block tile 256M x 256N, wave tile 128M x 64N. Grid 32bm x 8bn = 256 = 8*32.
// XCD mapping: bn-per-XCD (B panel L2-resident).
__global__ __launch_bounds__(512, 2) void gemm2_kernel(
    const u16* __restrict__ act,   // [8192][5504] bf16
    const u16* __restrict__ WdT,   // [2048][5504] bf16
    const float* __restrict__ bd,  // [2048]
    const float* __restrict__ selW,
    float* __restrict__ Yslot)     // [8192][2048] fp32 slot-major
{
  __shared__ u16 AL[2][2][8192];   // 64 KB
  __shared__ u16 BL[2][2][8192];   // 64 KB

  const int id = blockIdx.x;                  // 256 = 8 * 32
  const int wg = (id & 7) * 32 + (id >> 3);
  const int bm = wg & 31, bn = wg >> 5;

  const int tid = threadIdx.x;
  const int lane = tid & 63, wid = tid >> 6;
  const int wm = wid >> 2, wn = wid & 3;
  const int fr = lane & 15, ck = lane >> 4;
  const int sw0 = (ck ^ (fr & 7)) * 8;
  const int sw1 = sw0 ^ 32;
  const int rA = (wm * 64 + fr) * 64;
  const int rB = (wn * 32 + fr) * 64;

  const int sr = tid >> 3;
  const int sq = (tid & 7) ^ (sr & 7);
  const u16* aS0 = act + (size_t)(bm * 256 + sr) * ACT_P + sq * 8;
  const u16* aS1 = aS0 + (size_t)128 * ACT_P;
  const u16* bS0 = WdT + (size_t)(bn * 256 + sr) * ACT_P + sq * 8;
  const u16* bS1 = bS0 + (size_t)128 * ACT_P;

#define ST_A0(kt) { u16* d = &AL[(kt)&1][0][tid*8]; \
    STG(aS0 + (kt)*64, d); STG(aS0 + (kt)*64 + (size_t)64*ACT_P, d + 4096); }
#define ST_A1(kt) { u16* d = &AL[(kt)&1][1][tid*8]; \
    STG(aS1 + (kt)*64, d); STG(aS1 + (kt)*64 + (size_t)64*ACT_P, d + 4096); }
#define ST_B0(kt) { u16* d = &BL[(kt)&1][0][tid*8]; \
    STG(bS0 + (kt)*64, d); STG(bS0 + (kt)*64 + (size_t)64*ACT_P, d + 4096); }
#define ST_B1(kt) { u16* d = &BL[(kt)&1][1][tid*8]; \
    STG(bS1 + (kt)*64, d); STG(bS1 + (kt)*64 + (size_t)64*ACT_P, d + 4096); }

  f32x4 acc[8][4];
  const f32x4 z4 = {0.f, 0.f, 0.f, 0.f};
#pragma unroll
  for (int i = 0; i < 8; ++i)
#pragma unroll
    for (int n = 0; n < 4; ++n) acc[i][n] = z4;

  bf16x8 af[4][2], b0[2][2], b1[2][2];

  ST_A0(0) ST_B0(0) ST_B1(0) ST_A1(0)
  WAITV4(); BAR(); SCHED0();

  for (int kt = 0; kt < NT2; ++kt) {
    const u16* A0 = AL[kt & 1][0];
    const u16* A1 = AL[kt & 1][1];
    const u16* B0 = BL[kt & 1][0];
    const u16* B1 = BL[kt & 1][1];
    const int st = (kt + 1 < NT2);
    // ---- P0: read A0 + B0; stage A0'; MFMA acc[0-3][0-1] (16)
#pragma unroll
    for (int i = 0; i < 4; ++i) {
      af[i][0] = *(const bf16x8*)&A0[rA + i * 1024 + sw0];
      af[i][1] = *(const bf16x8*)&A0[rA + i * 1024 + sw1];
    }
#pragma unroll
    for (int n = 0; n < 2; ++n) {
      b0[n][0] = *(const bf16x8*)&B0[rB + n * 1024 + sw0];
      b0[n][1] = *(const bf16x8*)&B0[rB + n * 1024 + sw1];
    }
    if (st) ST_A0(kt + 1)
    PRIO1();
#pragma unroll
    for (int ks = 0; ks < 2; ++ks)
#pragma unroll
      for (int i = 0; i < 4; ++i)
#pragma unroll
        for (int n = 0; n < 2; ++n)
          acc[i][n] = MFMA(af[i][ks], b0[n][ks], acc[i][n]);
    PRIO0();
    if (st) { WAITV4(); } else { WAITV2(); }
    BAR(); SCHED0();
    // ---- P1: read B1; stage B0'+B1'; MFMA acc[0-3][2-3] (16)
#pragma unroll
    for (int n = 0; n < 2; ++n) {
      b1[n][0] = *(const bf16x8*)&B1[rB + n * 1024 + sw0];
      b1[n][1] = *(const bf16x8*)&B1[rB + n * 1024 + sw1];
    }
    if (st) { ST_B0(kt + 1) ST_B1(kt + 1) }
    PRIO1();
#pragma unroll
    for (int ks = 0; ks < 2; ++ks)
#pragma unroll
      for (int i = 0; i < 4; ++i)
#pragma unroll
        for (int n = 0; n < 2; ++n)
          acc[i][2 + n] = MFMA(af[i][ks], b1[n][ks], acc[i][2 + n]);
    PRIO0();
    if (st) { WAITV6(); } else { WAITV0(); }
    BAR(); SCHED0();
    // ---- P2: read A1; stage A1'; MFMA acc[4-7][0-3] (32)
#pragma unroll
    for (int i = 0; i < 4; ++i) {
      af[i][0] = *(const bf16x8*)&A1[rA + i * 1024 + sw0];
      af[i][1] = *(const bf16x8*)&A1[rA + i * 1024 + sw1];
    }
    if (st) ST_A1(kt + 1)
    PRIO1();
#pragma unroll
    for (int ks = 0; ks < 2; ++ks)
#pragma unroll
      for (int i = 0; i < 4; ++i)
#pragma unroll
        for (int n = 0; n < 2; ++n) {
          acc[4 + i][n]     = MFMA(af[i][ks], b0[n][ks], acc[4 + i][n]);
          acc[4 + i][2 + n] = MFMA(af[i][ks], b1[n][ks], acc[4 + i][2 + n]);
        }
    PRIO0();
    WAITV4();
    BAR(); SCHED0();
  }

  // epilogue: weighted dense store (no atomics)
#pragma unroll
  for (int f = 0; f < 8; ++f) {
    const int rbase = bm * 256 + (f >> 2) * 128 + wm * 64 + (f & 3) * 16 + ck * 4;
#pragma unroll
    for (int v = 0; v < 4; ++v) {
      const int srow = rbase + v;
      const float w = selW[srow];
      float* yrow = Yslot + (size_t)srow * HDIM;
#pragma unroll
      for (int n = 0; n < 4; ++n) {
        const int col = bn * 256 + (n >> 1) * 128 + wn * 32 + (n & 1) * 16 + fr;
        yrow[col] = w * (acc[f][n][v] + bd[col]);
      }
    }
  }
#undef ST_A0
#undef ST_A1
#undef ST_B0
#undef ST_B1
}

// ---------------- scatter: y[tok] = sum over experts of Yslot[inv[e][tok]]
__global__ __launch_bounds__(256) void scatter_kernel(const float* __restrict__ Yslot,
    const int* __restrict__ inv, float* __restrict__ y)
{
  const int t = blockIdx.x;
  const int c = threadIdx.x * 8;
  float4 a0 = {0.f,0.f,0.f,0.f}, a1 = {0.f,0.f,0.f,0.f};
#pragma unroll
  for (int e = 0; e < 8; ++e) {
    const int s = inv[e * N_TOK + t];
    if (s >= 0) {
      const float4* p = (const float4*)(Yslot + (size_t)s * HDIM + c);
      float4 v0 = p[0], v1 = p[1];
      a0.x += v0.x; a0.y += v0.y; a0.z += v0.z; a0.w += v0.w;
      a1.x += v1.x; a1.y += v1.y; a1.z += v1.z; a1.w += v1.w;
    }
  }
  float4* yp = (float4*)(y + (size_t)t * HDIM + c);
  yp[0] = a0; yp[1] = a1;
}

extern "C" void kernel_launch(void* const* d_in, const int* in_sizes, int n_in,
                              void* d_out, int out_size, void* d_ws, size_t ws_size,
                              hipStream_t stream) {
  const float* x      = (const float*)d_in[0];
  const float* rw     = (const float*)d_in[1];
  const float* rb     = (const float*)d_in[2];
  const float* w_gate = (const float*)d_in[3];
  const float* b_gate = (const float*)d_in[4];
  const float* w_up   = (const float*)d_in[5];
  const float* b_up   = (const float*)d_in[6];
  const float* w_down = (const float*)d_in[7];
  const float* b_down = (const float*)d_in[8];
  float* y = (float*)d_out;

  // Workspace layout (max end 180,158,464 B; aliasing by lifetime):
  //  [0,32K)        selTok ; [32K,64K) selW ; [64K,320K) inv
  //  [320K,90.5M)   act [8192][5504] bf16 (gemm1 -> gemm2)
  //  [90.5M,124.06M) Xsel (gather->gemm1); WdT aliases (post-gemm1)
  //  [113.05M,180.2M) Yslot f32 (gemm2->scatter); overlays SmT/WgT/WuT
  //  [124.06M,124.3M) SmT ; [124.3M,146.9M) WgT ; [146.9M,169.4M) WuT
  uint8_t* ws = (uint8_t*)d_ws;
  uint32_t* selTok = (uint32_t*)(ws + 0);
  float*    selW   = (float*)(ws + 32768);
  int*      inv    = (int*)(ws + 65536);
  u16*      act    = (u16*)(ws + 327680);
  u16*      Xsel   = (u16*)(ws + 90505216ull);
  u16*      WdT    = (u16*)(ws + 90505216ull);
  float*    Yslot  = (float*)(ws + 113049600ull);
  float*    SmT    = (float*)(ws + 124059648ull);
  u16*      WgT    = (u16*)(ws + 124321792ull);
  u16*      WuT    = (u16*)(ws + 146866176ull);

  hipMemsetAsync(inv, 0xFF, NEXP * N_TOK * sizeof(int), stream);
  transpose_convert_gu<<<dim3(172, 64, 2), dim3(32, 8), 0, stream>>>(w_gate, w_up, WgT, WuT);
  router_kernel<<<N_TOK / 4, 256, 0, stream>>>(x, rw, rb, SmT);
  select_topk<<<NEXP, 1024, 0, stream>>>(SmT, selTok, selW, inv);
  gather_kernel<<<N_TOK, 256, 0, stream>>>(x, selTok, Xsel);
  gemm1_kernel<<<43 * 32, 512, 0, stream>>>(Xsel, WgT, WuT, b_gate, b_up, act);
  transpose_convert<<<dim3(64, 172), dim3(32, 8), 0, stream>>>(w_down, DFF, 2048, WdT, ACT_P);
  gemm2_kernel<<<8 * 32, 512, 0, stream>>>(act, WdT, b_down, selW, Yslot);
  scatter_kernel<<<N_TOK, 256, 0, stream>>>(Yslot, inv, y);
}